// Round 13
// baseline (237.461 us; speedup 1.0000x reference)
//
#include <hip/hip_runtime.h>

#define NN 100000
#define NE 1200000
#define NG 512
#define NSEG (3 * NN)
#define CHUNK 1024
#define NCHUNK ((NSEG + CHUNK - 1) / CHUNK)

typedef __bf16 bf16x8 __attribute__((ext_vector_type(8)));
typedef float f32x4 __attribute__((ext_vector_type(4)));

// ---- workspace layout (bytes), all 16B-aligned ----
static constexpr size_t AGG_OFF   = 0;                                  // 3*NN*64 f32
static constexpr size_t AGG_BYTES = (size_t)NSEG * 64 * 4;              // 76,800,000
static constexpr size_t HIST_OFF  = AGG_OFF + AGG_BYTES;                // NSEG ints (hist -> end)
static constexpr size_t START_OFF = HIST_OFF + (size_t)NSEG * 4;        // NSEG ints
static constexpr size_t CSUM_OFF  = START_OFF + (size_t)NSEG * 4;       // NCHUNK ints
static constexpr size_t ESRC_OFF  = CSUM_OFF + 4096;                    // NE ints (packed src|cb<<17)
static constexpr size_t POOL_OFF  = ESRC_OFF + (size_t)NE * 4;          // NG*64 f32
static constexpr size_t H1_OFF    = POOL_OFF + (size_t)NG * 64 * 4;     // NN*64 f32
static constexpr size_t H2_OFF    = H1_OFF + (size_t)NN * 64 * 4;       // NN*64 f32
static constexpr size_t WT1H_OFF  = H2_OFF + (size_t)NN * 64 * 4;       // 64*128 bf16
static constexpr size_t WT1L_OFF  = WT1H_OFF + 64 * 128 * 2;
static constexpr size_t WT2H_OFF  = WT1L_OFF + 64 * 128 * 2;            // 64*256 bf16
static constexpr size_t WT2L_OFF  = WT2H_OFF + 64 * 256 * 2;
static constexpr size_t TAB_OFF   = WT2L_OFF + 64 * 256 * 2;            // 256*32 f32 (32KB)
static constexpr size_t CB_OFF    = TAB_OFF + 256 * 32 * 4;             // NN bytes
static constexpr size_t RS_OFF    = ((CB_OFF + NN + 15) / 16) * 16;     // NE uints (rank<<19|seg)

// async global->LDS, 16B per lane; LDS dest = wave-uniform base + lane*16
__device__ __forceinline__ void async_copy16(void* lds, const void* g) {
    __builtin_amdgcn_global_load_lds(
        (const __attribute__((address_space(1))) void*)g,
        (__attribute__((address_space(3))) void*)lds, 16, 0, 0);
}

// non-temporal float4 store (nt flag: minimize L2 pollution for write-once streams)
__device__ __forceinline__ void nt_store4(float* p, float4 v) {
    f32x4 x = {v.x, v.y, v.z, v.w};
    __builtin_nontemporal_store(x, (f32x4*)p);
}

__device__ __forceinline__ void prepw_elem(const float* root, const float* w,
                                           __bf16* wh, __bf16* wl, int cin, int t) {
    int kt = 4 * cin;
    if (t >= 64 * kt) return;
    int j = t / kt, k = t % kt;
    int sidx = k / cin, kk = k % cin;
    float v = (sidx == 0) ? root[kk * 64 + j]
                          : w[((size_t)(sidx - 1) * cin + kk) * 64 + j];
    __bf16 h = (__bf16)v;
    wh[t] = h;
    wl[t] = (__bf16)(v - (float)h);
}

// ---- fused prep: prepw1 (blocks 0..31), prepw2 (32..95), cbtable (96), node_cb (97..)
__global__ __launch_bounds__(256)
void k_prep_all(const int* __restrict__ x, const float* __restrict__ se,
                const float* __restrict__ ce, const float* __restrict__ pw,
                const float* __restrict__ pb,
                const float* __restrict__ root1, const float* __restrict__ w1,
                const float* __restrict__ root2, const float* __restrict__ w2,
                __bf16* __restrict__ wh1, __bf16* __restrict__ wl1,
                __bf16* __restrict__ wh2, __bf16* __restrict__ wl2,
                float* __restrict__ table, unsigned char* __restrict__ cb) {
    int b = blockIdx.x, t = threadIdx.x;
    if (b < 32) {
        prepw_elem(root1, w1, wh1, wl1, 32, b * 256 + t);
    } else if (b < 96) {
        prepw_elem(root2, w2, wh2, wl2, 64, (b - 32) * 256 + t);
    } else if (b == 96) {
        __shared__ float sW[16 * 32];
        __shared__ float sB[32];
        for (int i = t; i < 512; i += 256) sW[i] = pw[i];
        if (t < 32) sB[t] = pb[t];
        __syncthreads();
        int cmb = t, s = cmb >> 4, c = cmb & 15;
        float in[16];
#pragma unroll
        for (int k = 0; k < 8; k++) in[k] = se[s * 8 + k];
#pragma unroll
        for (int k = 0; k < 8; k++) in[8 + k] = ce[c * 8 + k];
        float acc[32];
#pragma unroll
        for (int j = 0; j < 32; j++) acc[j] = sB[j];
#pragma unroll
        for (int k = 0; k < 16; k++) {
            float hv = in[k];
#pragma unroll
            for (int j = 0; j < 32; j++) acc[j] += hv * sW[k * 32 + j];
        }
        float* o = table + (size_t)cmb * 32;
#pragma unroll
        for (int j = 0; j < 32; j += 4)
            *(float4*)(o + j) = make_float4(fmaxf(acc[j], 0.f), fmaxf(acc[j + 1], 0.f),
                                            fmaxf(acc[j + 2], 0.f), fmaxf(acc[j + 3], 0.f));
    } else {
        int n = (b - 97) * 256 + t;
        if (n < NN) cb[n] = (unsigned char)(x[2 * n] * 16 + x[2 * n + 1]);
    }
}

// ---- phase A: per-(rel,dst) histogram + per-edge rank memo
__global__ __launch_bounds__(256)
void k_rank(const int* __restrict__ ei, const int* __restrict__ et,
            int* __restrict__ hist, unsigned int* __restrict__ rs) {
    int e = blockIdx.x * 256 + threadIdx.x;
    if (e >= NE) return;
    int d = ei[NE + e];
    int r = et[e];
    int seg = r * NN + d;
    unsigned int rank = (unsigned int)atomicAdd(&hist[seg], 1);
    rs[e] = (rank << 19) | (unsigned int)seg;
}

// ---- scan pass 1: per-chunk sums
__global__ __launch_bounds__(256)
void k_chunksum(const int* __restrict__ hist, int* __restrict__ csum) {
    __shared__ int s[256];
    int b = blockIdx.x, t = threadIdx.x;
    int base = b * CHUNK + t * 4;
    int sum = 0;
#pragma unroll
    for (int k = 0; k < 4; k++) {
        int i = base + k;
        if (i < NSEG) sum += hist[i];
    }
    s[t] = sum;
    __syncthreads();
    for (int off = 128; off > 0; off >>= 1) {
        if (t < off) s[t] += s[t + off];
        __syncthreads();
    }
    if (t == 0) csum[b] = s[0];
}

// ---- scan pass 2: exclusive scan of chunk sums
__global__ __launch_bounds__(512)
void k_chunkscan(int* __restrict__ csum) {
    __shared__ int s[512];
    int t = threadIdx.x;
    int v = (t < NCHUNK) ? csum[t] : 0;
    s[t] = v;
    __syncthreads();
    for (int off = 1; off < 512; off <<= 1) {
        int x = (t >= off) ? s[t - off] : 0;
        __syncthreads();
        s[t] += x;
        __syncthreads();
    }
    if (t < NCHUNK) csum[t] = s[t] - v;   // exclusive
}

// ---- scan pass 3: local exclusive scan; start[]; hist[] -> end[]
__global__ __launch_bounds__(256)
void k_localscan(int* __restrict__ hist_end, const int* __restrict__ csum,
                 int* __restrict__ start) {
    __shared__ int s[256];
    int b = blockIdx.x, t = threadIdx.x;
    int base = b * CHUNK + t * 4;
    int v[4];
    int s4 = 0;
#pragma unroll
    for (int k = 0; k < 4; k++) {
        int i = base + k;
        v[k] = (i < NSEG) ? hist_end[i] : 0;
        s4 += v[k];
    }
    s[t] = s4;
    __syncthreads();
    for (int off = 1; off < 256; off <<= 1) {
        int x = (t >= off) ? s[t - off] : 0;
        __syncthreads();
        s[t] += x;
        __syncthreads();
    }
    int excl = s[t] - s4 + csum[b];
#pragma unroll
    for (int k = 0; k < 4; k++) {
        int i = base + k;
        if (i < NSEG) {
            start[i] = excl;
            hist_end[i] = excl + v[k];   // segment end
        }
        excl += v[k];
    }
}

// ---- phase B: atomic-free CSR scatter: esrc[start[seg]+rank] = src | cb[src]<<17
__global__ __launch_bounds__(256)
void k_fill2(const int* __restrict__ ei, const unsigned char* __restrict__ cb,
             const int* __restrict__ start, const unsigned int* __restrict__ rs,
             int* __restrict__ esrc) {
    int e = blockIdx.x * 256 + threadIdx.x;
    if (e >= NE) return;
    int s = ei[e];
    unsigned int v = rs[e];
    int seg = (int)(v & 0x7FFFFu);
    int pos = start[seg] + (int)(v >> 19);
    esrc[pos] = s | ((int)cb[s] << 17);
}

// ---- layer-1 gather from 256-row combo table (L1/L2-resident); nt agg store
__global__ __launch_bounds__(256)
void k_gather_t(const int* __restrict__ start, const int* __restrict__ end,
                const int* __restrict__ esrc, const float* __restrict__ table,
                float* __restrict__ agg) {
    int tid = blockIdx.x * 256 + threadIdx.x;
    int seg = tid >> 3;
    int p = tid & 7;
    if (seg >= NSEG) return;
    int st = start[seg], en = end[seg];
    float4 acc = make_float4(0.f, 0.f, 0.f, 0.f);
    int i = st;
    for (; i + 4 <= en; i += 4) {
        int v0 = esrc[i], v1 = esrc[i + 1], v2 = esrc[i + 2], v3 = esrc[i + 3];
        float4 a = *(const float4*)(table + ((v0 >> 17) & 0xFF) * 32 + p * 4);
        float4 b = *(const float4*)(table + ((v1 >> 17) & 0xFF) * 32 + p * 4);
        float4 c = *(const float4*)(table + ((v2 >> 17) & 0xFF) * 32 + p * 4);
        float4 d = *(const float4*)(table + ((v3 >> 17) & 0xFF) * 32 + p * 4);
        acc.x += (a.x + b.x) + (c.x + d.x);
        acc.y += (a.y + b.y) + (c.y + d.y);
        acc.z += (a.z + b.z) + (c.z + d.z);
        acc.w += (a.w + b.w) + (c.w + d.w);
    }
    for (; i < en; i++) {
        int v = esrc[i];
        float4 a = *(const float4*)(table + ((v >> 17) & 0xFF) * 32 + p * 4);
        acc.x += a.x; acc.y += a.y; acc.z += a.z; acc.w += a.w;
    }
    int c = en - st;
    float inv = 1.f / (float)(c > 1 ? c : 1);
    acc.x *= inv; acc.y *= inv; acc.z *= inv; acc.w *= inv;
    nt_store4(agg + (size_t)seg * 32 + p * 4, acc);
}

// ---- layer-2 gather: 8 threads/seg, 32B/thread, unroll-4; nt agg stores
// (nt keeps the 75MB agg write stream out of L2 so h1 (25.6MB) stays resident)
__global__ __launch_bounds__(256)
void k_gather64(const int* __restrict__ start, const int* __restrict__ end,
                const int* __restrict__ esrc, const float* __restrict__ h,
                float* __restrict__ agg) {
    int tid = blockIdx.x * 256 + threadIdx.x;
    int seg = tid >> 3;
    int p = tid & 7;
    if (seg >= NSEG) return;
    int st = start[seg], en = end[seg];
    float4 a0 = make_float4(0.f, 0.f, 0.f, 0.f);
    float4 a1 = make_float4(0.f, 0.f, 0.f, 0.f);
    int i = st;
    for (; i + 4 <= en; i += 4) {
        int s0 = esrc[i] & 0x1FFFF, s1 = esrc[i + 1] & 0x1FFFF;
        int s2 = esrc[i + 2] & 0x1FFFF, s3 = esrc[i + 3] & 0x1FFFF;
        const float* b0 = h + (size_t)s0 * 64 + p * 8;
        const float* b1 = h + (size_t)s1 * 64 + p * 8;
        const float* b2 = h + (size_t)s2 * 64 + p * 8;
        const float* b3 = h + (size_t)s3 * 64 + p * 8;
        float4 v0a = *(const float4*)b0, v0b = *(const float4*)(b0 + 4);
        float4 v1a = *(const float4*)b1, v1b = *(const float4*)(b1 + 4);
        float4 v2a = *(const float4*)b2, v2b = *(const float4*)(b2 + 4);
        float4 v3a = *(const float4*)b3, v3b = *(const float4*)(b3 + 4);
        a0.x += (v0a.x + v1a.x) + (v2a.x + v3a.x);
        a0.y += (v0a.y + v1a.y) + (v2a.y + v3a.y);
        a0.z += (v0a.z + v1a.z) + (v2a.z + v3a.z);
        a0.w += (v0a.w + v1a.w) + (v2a.w + v3a.w);
        a1.x += (v0b.x + v1b.x) + (v2b.x + v3b.x);
        a1.y += (v0b.y + v1b.y) + (v2b.y + v3b.y);
        a1.z += (v0b.z + v1b.z) + (v2b.z + v3b.z);
        a1.w += (v0b.w + v1b.w) + (v2b.w + v3b.w);
    }
    for (; i < en; i++) {
        int s = esrc[i] & 0x1FFFF;
        const float* b = h + (size_t)s * 64 + p * 8;
        float4 va = *(const float4*)b, vb = *(const float4*)(b + 4);
        a0.x += va.x; a0.y += va.y; a0.z += va.z; a0.w += va.w;
        a1.x += vb.x; a1.y += vb.y; a1.z += vb.z; a1.w += vb.w;
    }
    int c = en - st;
    float inv = 1.f / (float)(c > 1 ? c : 1);
    a0.x *= inv; a0.y *= inv; a0.z *= inv; a0.w *= inv;
    a1.x *= inv; a1.y *= inv; a1.z *= inv; a1.w *= inv;
    float* o = agg + (size_t)seg * 64 + p * 8;
    nt_store4(o, a0);
    nt_store4(o + 4, a1);
}

// split 8 fp32 -> hi/lo bf16x8 fragments (hi+lo represents x to ~2^-18 rel)
__device__ __forceinline__ void split8(float4 a0, float4 a1, bf16x8& hi, bf16x8& lo) {
    float v[8] = {a0.x, a0.y, a0.z, a0.w, a1.x, a1.y, a1.z, a1.w};
#pragma unroll
    for (int i = 0; i < 8; i++) {
        __bf16 h = (__bf16)v[i];
        hi[i] = h;
        lo[i] = (__bf16)(v[i] - (float)h);
    }
}

// ---- combine via split-bf16 MFMA. TAB=true: chunk-0 rows come from table[cb[n]].
template <int CIN, bool TAB>
__global__ __launch_bounds__(256, 1)
void k_combine_m(const float* __restrict__ h_in, const unsigned char* __restrict__ cb,
                 const float* __restrict__ agg,
                 const __bf16* __restrict__ wh, const __bf16* __restrict__ wl,
                 const float* __restrict__ bias, float* __restrict__ h_out) {
    constexpr int KT = 4 * CIN;          // 128 or 256
    constexpr int NCHK = KT / 64;        // 2 or 4 chunks of K=64
    __shared__ float sIN[64 * 64];       // 16 KB
    __shared__ __bf16 sWH[64 * 64];      // 8 KB
    __shared__ __bf16 sWL[64 * 64];      // 8 KB

    const int tid = threadIdx.x;
    const int wave = tid >> 6;
    const int lane = tid & 63;
    const int cA = lane & 15;
    const int kg = lane >> 4;
    const int n0 = blockIdx.x * 64;

    f32x4 acc[4];
#pragma unroll
    for (int nb = 0; nb < 4; nb++) {
        float bv = bias[nb * 16 + cA];
        acc[nb][0] = bv; acc[nb][1] = bv; acc[nb][2] = bv; acc[nb][3] = bv;
    }

    for (int c = 0; c < NCHK; c++) {
        if (c) __syncthreads();
#pragma unroll
        for (int i = 0; i < 4; i++) {
            int F = tid + i * 256;
            int row = F >> 4, j = F & 15;
            int jor = j ^ (row & 7);
            int n = n0 + row; if (n > NN - 1) n = NN - 1;
            const float* src;
            if constexpr (CIN == 64) {
                src = (c == 0 ? h_in + (size_t)n * 64
                              : agg + ((size_t)(c - 1) * NN + n) * 64) + jor * 4;
            } else {
                int sidx = 2 * c + (jor >> 3);
                int jj = jor & 7;
                if (TAB && sidx == 0)
                    src = h_in + (size_t)cb[n] * 32 + jj * 4;   // h_in = combo table
                else
                    src = agg + ((size_t)(sidx - 1) * NN + n) * 32 + jj * 4;
            }
            async_copy16(sIN + (size_t)F * 4, src);
        }
#pragma unroll
        for (int i = 0; i < 2; i++) {
            int F = tid + i * 256;
            int col = F >> 3, s = F & 7;
            int sor = s ^ (col & 7);
            async_copy16(sWH + (size_t)F * 8, wh + (size_t)col * KT + c * 64 + sor * 8);
            async_copy16(sWL + (size_t)F * 8, wl + (size_t)col * KT + c * 64 + sor * 8);
        }
        __syncthreads();
#pragma unroll
        for (int ks = 0; ks < 2; ks++) {
            const int rowL = wave * 16 + cA;
            const int jA = ks * 8 + kg * 2;
            float4 a0 = ((const float4*)sIN)[rowL * 16 + (jA ^ (rowL & 7))];
            float4 a1 = ((const float4*)sIN)[rowL * 16 + ((jA + 1) ^ (rowL & 7))];
            bf16x8 ah, al;
            split8(a0, a1, ah, al);
            const int k8 = ks * 4 + kg;
#pragma unroll
            for (int nb = 0; nb < 4; nb++) {
                const int col = nb * 16 + cA;
                const int bs = col * 8 + (k8 ^ (col & 7));
                bf16x8 bh = ((const bf16x8*)sWH)[bs];
                bf16x8 bl = ((const bf16x8*)sWL)[bs];
                acc[nb] = __builtin_amdgcn_mfma_f32_16x16x32_bf16(ah, bh, acc[nb], 0, 0, 0);
                acc[nb] = __builtin_amdgcn_mfma_f32_16x16x32_bf16(al, bh, acc[nb], 0, 0, 0);
                acc[nb] = __builtin_amdgcn_mfma_f32_16x16x32_bf16(ah, bl, acc[nb], 0, 0, 0);
                acc[nb] = __builtin_amdgcn_mfma_f32_16x16x32_bf16(al, bl, acc[nb], 0, 0, 0);
            }
        }
    }
#pragma unroll
    for (int nb = 0; nb < 4; nb++) {
#pragma unroll
        for (int r = 0; r < 4; r++) {
            int n = n0 + wave * 16 + kg * 4 + r;
            if (n < NN)
                h_out[(size_t)n * 64 + nb * 16 + cA] = fmaxf(acc[nb][r], 0.f);
        }
    }
}

// ---- mean pool via binary search on sorted batch (no atomics)
__global__ __launch_bounds__(256)
void k_pool(const float* __restrict__ h, const int* __restrict__ batch,
            float* __restrict__ pool) {
    int g = blockIdx.x;
    auto lb = [&](int v) {
        int lo = 0, hi = NN;
        while (lo < hi) {
            int m = (lo + hi) >> 1;
            if (batch[m] < v) lo = m + 1; else hi = m;
        }
        return lo;
    };
    int st = lb(g), en = lb(g + 1);
    int col = threadIdx.x & 63, chunk = threadIdx.x >> 6;
    float acc = 0.f;
    for (int n = st + chunk; n < en; n += 4) acc += h[(size_t)n * 64 + col];
    __shared__ float s[256];
    s[threadIdx.x] = acc;
    __syncthreads();
    if (chunk == 0) {
        float tot = s[col] + s[64 + col] + s[128 + col] + s[192 + col];
        int c = en - st;
        pool[g * 64 + col] = tot / (float)(c > 1 ? c : 1);
    }
}

// ---- classifier
__global__ __launch_bounds__(256)
void k_final(const float* __restrict__ pool, const float* __restrict__ cw,
             const float* __restrict__ cb, float* __restrict__ out) {
    int t = blockIdx.x * blockDim.x + threadIdx.x;
    if (t >= NG * 10) return;
    int g = t / 10, j = t % 10;
    float acc = 0.f;
#pragma unroll
    for (int k = 0; k < 64; k++) acc += pool[g * 64 + k] * cw[k * 10 + j];
    out[t] = cb[j] + acc;
}

extern "C" void kernel_launch(void* const* d_in, const int* in_sizes, int n_in,
                              void* d_out, int out_size, void* d_ws, size_t ws_size,
                              hipStream_t stream) {
    const int* x      = (const int*)d_in[0];
    const int* ei     = (const int*)d_in[1];
    const int* et     = (const int*)d_in[2];
    const int* batch  = (const int*)d_in[3];
    const float* se   = (const float*)d_in[4];
    const float* ce   = (const float*)d_in[5];
    const float* pw   = (const float*)d_in[6];
    const float* pb   = (const float*)d_in[7];
    const float* w1   = (const float*)d_in[8];
    const float* root1= (const float*)d_in[9];
    const float* b1   = (const float*)d_in[10];
    const float* w2   = (const float*)d_in[11];
    const float* root2= (const float*)d_in[12];
    const float* b2   = (const float*)d_in[13];
    const float* cw   = (const float*)d_in[14];
    const float* cbias= (const float*)d_in[15];
    float* out = (float*)d_out;

    char* ws = (char*)d_ws;
    float* agg   = (float*)(ws + AGG_OFF);
    int*   hist  = (int*)(ws + HIST_OFF);    // histogram -> end[] after localscan
    int*   start = (int*)(ws + START_OFF);
    int*   csum  = (int*)(ws + CSUM_OFF);
    int*   esrc  = (int*)(ws + ESRC_OFF);
    float* pool  = (float*)(ws + POOL_OFF);
    float* h1    = (float*)(ws + H1_OFF);
    float* h2    = (float*)(ws + H2_OFF);
    __bf16* wt1h = (__bf16*)(ws + WT1H_OFF);
    __bf16* wt1l = (__bf16*)(ws + WT1L_OFF);
    __bf16* wt2h = (__bf16*)(ws + WT2H_OFF);
    __bf16* wt2l = (__bf16*)(ws + WT2L_OFF);
    float* table = (float*)(ws + TAB_OFF);
    unsigned char* cbarr = (unsigned char*)(ws + CB_OFF);
    unsigned int* rs = (unsigned int*)(ws + RS_OFF);

    // zero the histogram only
    (void)hipMemsetAsync(hist, 0, (size_t)NSEG * 4, stream);

    // fused prep: prepw1 | prepw2 | cbtable | node_cb
    int prep_blocks = 97 + (NN + 255) / 256;
    k_prep_all<<<prep_blocks, 256, 0, stream>>>(x, se, ce, pw, pb, root1, w1, root2, w2,
                                                wt1h, wt1l, wt2h, wt2l, table, cbarr);

    // CSR build (phase A: rank + hist; scan; phase B: atomic-free scatter)
    k_rank<<<(NE + 255) / 256, 256, 0, stream>>>(ei, et, hist, rs);
    k_chunksum<<<NCHUNK, 256, 0, stream>>>(hist, csum);
    k_chunkscan<<<1, 512, 0, stream>>>(csum);
    k_localscan<<<NCHUNK, 256, 0, stream>>>(hist, csum, start);
    k_fill2<<<(NE + 255) / 256, 256, 0, stream>>>(ei, cbarr, start, rs, esrc);

    // layer 1 (gather from combo table; combine stages chunk-0 from table via cb)
    k_gather_t<<<(NSEG * 8 + 255) / 256, 256, 0, stream>>>(start, hist, esrc, table, agg);
    k_combine_m<32, true><<<(NN + 63) / 64, 256, 0, stream>>>(table, cbarr, agg,
                                                              wt1h, wt1l, b1, h1);
    // layer 2
    k_gather64<<<(NSEG * 8 + 255) / 256, 256, 0, stream>>>(start, hist, esrc, h1, agg);
    k_combine_m<64, false><<<(NN + 63) / 64, 256, 0, stream>>>(h1, cbarr, agg,
                                                               wt2h, wt2l, b2, h2);

    // pooling + classifier
    k_pool<<<NG, 256, 0, stream>>>(h2, batch, pool);
    k_final<<<(NG * 10 + 255) / 256, 256, 0, stream>>>(pool, cw, cbias, out);
}

// Round 14
// 199.222 us; speedup vs baseline: 1.1919x; 1.1919x over previous
//
#include <hip/hip_runtime.h>

#define NN 100000
#define NE 1200000
#define NG 512
#define NSEG (3 * NN)
#define CHUNK 1024
#define NCHUNK ((NSEG + CHUNK - 1) / CHUNK)

typedef __bf16 bf16x8 __attribute__((ext_vector_type(8)));
typedef float f32x4 __attribute__((ext_vector_type(4)));

// ---- workspace layout (bytes), all 16B-aligned ----
// agg region: layer-1 fp32 [NSEG][32] (38.4MB) then reused as layer-2 bf16 [NSEG][64] (38.4MB)
static constexpr size_t AGG_OFF   = 0;
static constexpr size_t AGG_BYTES = (size_t)NSEG * 32 * 4;              // 38,400,000
static constexpr size_t HIST_OFF  = AGG_OFF + AGG_BYTES;                // NSEG ints (hist -> end)
static constexpr size_t START_OFF = HIST_OFF + (size_t)NSEG * 4;        // NSEG ints
static constexpr size_t CSUM_OFF  = START_OFF + (size_t)NSEG * 4;       // NCHUNK ints
static constexpr size_t ESRC_OFF  = CSUM_OFF + 4096;                    // NE ints (packed src|cb<<17)
static constexpr size_t POOL_OFF  = ESRC_OFF + (size_t)NE * 4;          // NG*64 f32
static constexpr size_t H1_OFF    = POOL_OFF + (size_t)NG * 64 * 4;     // NN*64 bf16 (12.8MB)
static constexpr size_t H2_OFF    = H1_OFF + (size_t)NN * 64 * 2;       // NN*64 f32
static constexpr size_t WT1H_OFF  = H2_OFF + (size_t)NN * 64 * 4;       // 64*128 bf16
static constexpr size_t WT1L_OFF  = WT1H_OFF + 64 * 128 * 2;
static constexpr size_t WT2H_OFF  = WT1L_OFF + 64 * 128 * 2;            // 64*256 bf16
static constexpr size_t WT2L_OFF  = WT2H_OFF + 64 * 256 * 2;
static constexpr size_t TAB_OFF   = WT2L_OFF + 64 * 256 * 2;            // 256*32 f32 (32KB)
static constexpr size_t CB_OFF    = TAB_OFF + 256 * 32 * 4;             // NN bytes
static constexpr size_t RS_OFF    = ((CB_OFF + NN + 15) / 16) * 16;     // NE uints (rank<<19|seg)

// async global->LDS, 16B per lane; LDS dest = wave-uniform base + lane*16
__device__ __forceinline__ void async_copy16(void* lds, const void* g) {
    __builtin_amdgcn_global_load_lds(
        (const __attribute__((address_space(1))) void*)g,
        (__attribute__((address_space(3))) void*)lds, 16, 0, 0);
}

__device__ __forceinline__ void prepw_elem(const float* root, const float* w,
                                           __bf16* wh, __bf16* wl, int cin, int t) {
    int kt = 4 * cin;
    if (t >= 64 * kt) return;
    int j = t / kt, k = t % kt;
    int sidx = k / cin, kk = k % cin;
    float v = (sidx == 0) ? root[kk * 64 + j]
                          : w[((size_t)(sidx - 1) * cin + kk) * 64 + j];
    __bf16 h = (__bf16)v;
    wh[t] = h;
    wl[t] = (__bf16)(v - (float)h);
}

// ---- fused prep: prepw1 (blocks 0..31), prepw2 (32..95), cbtable (96), node_cb (97..)
__global__ __launch_bounds__(256)
void k_prep_all(const int* __restrict__ x, const float* __restrict__ se,
                const float* __restrict__ ce, const float* __restrict__ pw,
                const float* __restrict__ pb,
                const float* __restrict__ root1, const float* __restrict__ w1,
                const float* __restrict__ root2, const float* __restrict__ w2,
                __bf16* __restrict__ wh1, __bf16* __restrict__ wl1,
                __bf16* __restrict__ wh2, __bf16* __restrict__ wl2,
                float* __restrict__ table, unsigned char* __restrict__ cb) {
    int b = blockIdx.x, t = threadIdx.x;
    if (b < 32) {
        prepw_elem(root1, w1, wh1, wl1, 32, b * 256 + t);
    } else if (b < 96) {
        prepw_elem(root2, w2, wh2, wl2, 64, (b - 32) * 256 + t);
    } else if (b == 96) {
        __shared__ float sW[16 * 32];
        __shared__ float sB[32];
        for (int i = t; i < 512; i += 256) sW[i] = pw[i];
        if (t < 32) sB[t] = pb[t];
        __syncthreads();
        int cmb = t, s = cmb >> 4, c = cmb & 15;
        float in[16];
#pragma unroll
        for (int k = 0; k < 8; k++) in[k] = se[s * 8 + k];
#pragma unroll
        for (int k = 0; k < 8; k++) in[8 + k] = ce[c * 8 + k];
        float acc[32];
#pragma unroll
        for (int j = 0; j < 32; j++) acc[j] = sB[j];
#pragma unroll
        for (int k = 0; k < 16; k++) {
            float hv = in[k];
#pragma unroll
            for (int j = 0; j < 32; j++) acc[j] += hv * sW[k * 32 + j];
        }
        float* o = table + (size_t)cmb * 32;
#pragma unroll
        for (int j = 0; j < 32; j += 4)
            *(float4*)(o + j) = make_float4(fmaxf(acc[j], 0.f), fmaxf(acc[j + 1], 0.f),
                                            fmaxf(acc[j + 2], 0.f), fmaxf(acc[j + 3], 0.f));
    } else {
        int n = (b - 97) * 256 + t;
        if (n < NN) cb[n] = (unsigned char)(x[2 * n] * 16 + x[2 * n + 1]);
    }
}

// ---- phase A: per-(rel,dst) histogram + per-edge rank memo
__global__ __launch_bounds__(256)
void k_rank(const int* __restrict__ ei, const int* __restrict__ et,
            int* __restrict__ hist, unsigned int* __restrict__ rs) {
    int e = blockIdx.x * 256 + threadIdx.x;
    if (e >= NE) return;
    int d = ei[NE + e];
    int r = et[e];
    int seg = r * NN + d;
    unsigned int rank = (unsigned int)atomicAdd(&hist[seg], 1);
    rs[e] = (rank << 19) | (unsigned int)seg;
}

// ---- scan pass 1: per-chunk sums
__global__ __launch_bounds__(256)
void k_chunksum(const int* __restrict__ hist, int* __restrict__ csum) {
    __shared__ int s[256];
    int b = blockIdx.x, t = threadIdx.x;
    int base = b * CHUNK + t * 4;
    int sum = 0;
#pragma unroll
    for (int k = 0; k < 4; k++) {
        int i = base + k;
        if (i < NSEG) sum += hist[i];
    }
    s[t] = sum;
    __syncthreads();
    for (int off = 128; off > 0; off >>= 1) {
        if (t < off) s[t] += s[t + off];
        __syncthreads();
    }
    if (t == 0) csum[b] = s[0];
}

// ---- scan pass 2: exclusive scan of chunk sums
__global__ __launch_bounds__(512)
void k_chunkscan(int* __restrict__ csum) {
    __shared__ int s[512];
    int t = threadIdx.x;
    int v = (t < NCHUNK) ? csum[t] : 0;
    s[t] = v;
    __syncthreads();
    for (int off = 1; off < 512; off <<= 1) {
        int x = (t >= off) ? s[t - off] : 0;
        __syncthreads();
        s[t] += x;
        __syncthreads();
    }
    if (t < NCHUNK) csum[t] = s[t] - v;   // exclusive
}

// ---- scan pass 3: local exclusive scan; start[]; hist[] -> end[]
__global__ __launch_bounds__(256)
void k_localscan(int* __restrict__ hist_end, const int* __restrict__ csum,
                 int* __restrict__ start) {
    __shared__ int s[256];
    int b = blockIdx.x, t = threadIdx.x;
    int base = b * CHUNK + t * 4;
    int v[4];
    int s4 = 0;
#pragma unroll
    for (int k = 0; k < 4; k++) {
        int i = base + k;
        v[k] = (i < NSEG) ? hist_end[i] : 0;
        s4 += v[k];
    }
    s[t] = s4;
    __syncthreads();
    for (int off = 1; off < 256; off <<= 1) {
        int x = (t >= off) ? s[t - off] : 0;
        __syncthreads();
        s[t] += x;
        __syncthreads();
    }
    int excl = s[t] - s4 + csum[b];
#pragma unroll
    for (int k = 0; k < 4; k++) {
        int i = base + k;
        if (i < NSEG) {
            start[i] = excl;
            hist_end[i] = excl + v[k];   // segment end
        }
        excl += v[k];
    }
}

// ---- phase B: atomic-free CSR scatter: esrc[start[seg]+rank] = src | cb[src]<<17
__global__ __launch_bounds__(256)
void k_fill2(const int* __restrict__ ei, const unsigned char* __restrict__ cb,
             const int* __restrict__ start, const unsigned int* __restrict__ rs,
             int* __restrict__ esrc) {
    int e = blockIdx.x * 256 + threadIdx.x;
    if (e >= NE) return;
    int s = ei[e];
    unsigned int v = rs[e];
    int seg = (int)(v & 0x7FFFFu);
    int pos = start[seg] + (int)(v >> 19);
    esrc[pos] = s | ((int)cb[s] << 17);
}

// ---- layer-1 gather from 256-row combo table (L1/L2-resident); fp32 agg
__global__ __launch_bounds__(256)
void k_gather_t(const int* __restrict__ start, const int* __restrict__ end,
                const int* __restrict__ esrc, const float* __restrict__ table,
                float* __restrict__ agg) {
    int tid = blockIdx.x * 256 + threadIdx.x;
    int seg = tid >> 3;
    int p = tid & 7;
    if (seg >= NSEG) return;
    int st = start[seg], en = end[seg];
    float4 acc = make_float4(0.f, 0.f, 0.f, 0.f);
    int i = st;
    for (; i + 4 <= en; i += 4) {
        int v0 = esrc[i], v1 = esrc[i + 1], v2 = esrc[i + 2], v3 = esrc[i + 3];
        float4 a = *(const float4*)(table + ((v0 >> 17) & 0xFF) * 32 + p * 4);
        float4 b = *(const float4*)(table + ((v1 >> 17) & 0xFF) * 32 + p * 4);
        float4 c = *(const float4*)(table + ((v2 >> 17) & 0xFF) * 32 + p * 4);
        float4 d = *(const float4*)(table + ((v3 >> 17) & 0xFF) * 32 + p * 4);
        acc.x += (a.x + b.x) + (c.x + d.x);
        acc.y += (a.y + b.y) + (c.y + d.y);
        acc.z += (a.z + b.z) + (c.z + d.z);
        acc.w += (a.w + b.w) + (c.w + d.w);
    }
    for (; i < en; i++) {
        int v = esrc[i];
        float4 a = *(const float4*)(table + ((v >> 17) & 0xFF) * 32 + p * 4);
        acc.x += a.x; acc.y += a.y; acc.z += a.z; acc.w += a.w;
    }
    int c = en - st;
    float inv = 1.f / (float)(c > 1 ? c : 1);
    acc.x *= inv; acc.y *= inv; acc.z *= inv; acc.w *= inv;
    *(float4*)(agg + (size_t)seg * 32 + p * 4) = acc;
}

// ---- layer-2 gather: bf16 h1 rows (128B/edge), 8 threads/seg x 16B; bf16 agg out
__global__ __launch_bounds__(256)
void k_gather64(const int* __restrict__ start, const int* __restrict__ end,
                const int* __restrict__ esrc, const __bf16* __restrict__ h,
                __bf16* __restrict__ agg) {
    int tid = blockIdx.x * 256 + threadIdx.x;
    int seg = tid >> 3;
    int p = tid & 7;
    if (seg >= NSEG) return;
    int st = start[seg], en = end[seg];
    float acc[8];
#pragma unroll
    for (int j = 0; j < 8; j++) acc[j] = 0.f;
    int i = st;
    for (; i + 4 <= en; i += 4) {
        int s0 = esrc[i] & 0x1FFFF, s1 = esrc[i + 1] & 0x1FFFF;
        int s2 = esrc[i + 2] & 0x1FFFF, s3 = esrc[i + 3] & 0x1FFFF;
        bf16x8 v0 = *(const bf16x8*)(h + (size_t)s0 * 64 + p * 8);
        bf16x8 v1 = *(const bf16x8*)(h + (size_t)s1 * 64 + p * 8);
        bf16x8 v2 = *(const bf16x8*)(h + (size_t)s2 * 64 + p * 8);
        bf16x8 v3 = *(const bf16x8*)(h + (size_t)s3 * 64 + p * 8);
#pragma unroll
        for (int j = 0; j < 8; j++)
            acc[j] += ((float)v0[j] + (float)v1[j]) + ((float)v2[j] + (float)v3[j]);
    }
    for (; i < en; i++) {
        int s = esrc[i] & 0x1FFFF;
        bf16x8 v = *(const bf16x8*)(h + (size_t)s * 64 + p * 8);
#pragma unroll
        for (int j = 0; j < 8; j++) acc[j] += (float)v[j];
    }
    int c = en - st;
    float inv = 1.f / (float)(c > 1 ? c : 1);
    bf16x8 o;
#pragma unroll
    for (int j = 0; j < 8; j++) o[j] = (__bf16)(acc[j] * inv);
    *(bf16x8*)(agg + (size_t)seg * 64 + p * 8) = o;
}

// split 8 fp32 -> hi/lo bf16x8 fragments (hi+lo represents x to ~2^-18 rel)
__device__ __forceinline__ void split8(float4 a0, float4 a1, bf16x8& hi, bf16x8& lo) {
    float v[8] = {a0.x, a0.y, a0.z, a0.w, a1.x, a1.y, a1.z, a1.w};
#pragma unroll
    for (int i = 0; i < 8; i++) {
        __bf16 h = (__bf16)v[i];
        hi[i] = h;
        lo[i] = (__bf16)(v[i] - (float)h);
    }
}

// ---- layer-1 combine via split-bf16 MFMA (fp32 inputs from table/agg1); bf16 h1 out
__global__ __launch_bounds__(256, 1)
void k_combine_l1(const float* __restrict__ table, const unsigned char* __restrict__ cb,
                  const float* __restrict__ agg,
                  const __bf16* __restrict__ wh, const __bf16* __restrict__ wl,
                  const float* __restrict__ bias, __bf16* __restrict__ h_out) {
    constexpr int KT = 128;
    __shared__ float sIN[64 * 64];       // 16 KB
    __shared__ __bf16 sWH[64 * 64];      // 8 KB
    __shared__ __bf16 sWL[64 * 64];      // 8 KB

    const int tid = threadIdx.x;
    const int wave = tid >> 6;
    const int lane = tid & 63;
    const int cA = lane & 15;
    const int kg = lane >> 4;
    const int n0 = blockIdx.x * 64;

    f32x4 acc[4];
#pragma unroll
    for (int nb = 0; nb < 4; nb++) {
        float bv = bias[nb * 16 + cA];
        acc[nb][0] = bv; acc[nb][1] = bv; acc[nb][2] = bv; acc[nb][3] = bv;
    }

    for (int c = 0; c < 2; c++) {
        if (c) __syncthreads();
#pragma unroll
        for (int i = 0; i < 4; i++) {
            int F = tid + i * 256;
            int row = F >> 4, j = F & 15;
            int jor = j ^ (row & 7);
            int n = n0 + row; if (n > NN - 1) n = NN - 1;
            int sidx = 2 * c + (jor >> 3);
            int jj = jor & 7;
            const float* src = (sidx == 0)
                ? table + (size_t)cb[n] * 32 + jj * 4
                : agg + ((size_t)(sidx - 1) * NN + n) * 32 + jj * 4;
            async_copy16(sIN + (size_t)F * 4, src);
        }
#pragma unroll
        for (int i = 0; i < 2; i++) {
            int F = tid + i * 256;
            int col = F >> 3, s = F & 7;
            int sor = s ^ (col & 7);
            async_copy16(sWH + (size_t)F * 8, wh + (size_t)col * KT + c * 64 + sor * 8);
            async_copy16(sWL + (size_t)F * 8, wl + (size_t)col * KT + c * 64 + sor * 8);
        }
        __syncthreads();
#pragma unroll
        for (int ks = 0; ks < 2; ks++) {
            const int rowL = wave * 16 + cA;
            const int jA = ks * 8 + kg * 2;
            float4 a0 = ((const float4*)sIN)[rowL * 16 + (jA ^ (rowL & 7))];
            float4 a1 = ((const float4*)sIN)[rowL * 16 + ((jA + 1) ^ (rowL & 7))];
            bf16x8 ah, al;
            split8(a0, a1, ah, al);
            const int k8 = ks * 4 + kg;
#pragma unroll
            for (int nb = 0; nb < 4; nb++) {
                const int col = nb * 16 + cA;
                const int bs = col * 8 + (k8 ^ (col & 7));
                bf16x8 bh = ((const bf16x8*)sWH)[bs];
                bf16x8 bl = ((const bf16x8*)sWL)[bs];
                acc[nb] = __builtin_amdgcn_mfma_f32_16x16x32_bf16(ah, bh, acc[nb], 0, 0, 0);
                acc[nb] = __builtin_amdgcn_mfma_f32_16x16x32_bf16(al, bh, acc[nb], 0, 0, 0);
                acc[nb] = __builtin_amdgcn_mfma_f32_16x16x32_bf16(ah, bl, acc[nb], 0, 0, 0);
                acc[nb] = __builtin_amdgcn_mfma_f32_16x16x32_bf16(al, bl, acc[nb], 0, 0, 0);
            }
        }
    }
#pragma unroll
    for (int nb = 0; nb < 4; nb++) {
#pragma unroll
        for (int r = 0; r < 4; r++) {
            int n = n0 + wave * 16 + kg * 4 + r;
            if (n < NN)
                h_out[(size_t)n * 64 + nb * 16 + cA] = (__bf16)fmaxf(acc[nb][r], 0.f);
        }
    }
}

// ---- layer-2 combine: bf16 A (h1b / aggb) direct, split-bf16 weights; fp32 h2 out
__global__ __launch_bounds__(256, 1)
void k_combine_l2(const __bf16* __restrict__ h1b, const __bf16* __restrict__ aggb,
                  const __bf16* __restrict__ wh, const __bf16* __restrict__ wl,
                  const float* __restrict__ bias, float* __restrict__ h_out) {
    constexpr int KT = 256;
    __shared__ __bf16 sINb[64 * 64];     // 8 KB
    __shared__ __bf16 sWH[64 * 64];      // 8 KB
    __shared__ __bf16 sWL[64 * 64];      // 8 KB

    const int tid = threadIdx.x;
    const int wave = tid >> 6;
    const int lane = tid & 63;
    const int cA = lane & 15;
    const int kg = lane >> 4;
    const int n0 = blockIdx.x * 64;

    f32x4 acc[4];
#pragma unroll
    for (int nb = 0; nb < 4; nb++) {
        float bv = bias[nb * 16 + cA];
        acc[nb][0] = bv; acc[nb][1] = bv; acc[nb][2] = bv; acc[nb][3] = bv;
    }

    for (int c = 0; c < 4; c++) {
        if (c) __syncthreads();
        // stage A: 512 x 16B slots; slot (row, j ^ (row&7))
#pragma unroll
        for (int i = 0; i < 2; i++) {
            int F = tid + i * 256;
            int row = F >> 3, j = F & 7;
            int jor = j ^ (row & 7);
            int n = n0 + row; if (n > NN - 1) n = NN - 1;
            const __bf16* src = (c == 0)
                ? h1b + (size_t)n * 64 + jor * 8
                : aggb + ((size_t)(c - 1) * NN + n) * 64 + jor * 8;
            async_copy16(sINb + (size_t)F * 8, src);
        }
        // stage weights
#pragma unroll
        for (int i = 0; i < 2; i++) {
            int F = tid + i * 256;
            int col = F >> 3, s = F & 7;
            int sor = s ^ (col & 7);
            async_copy16(sWH + (size_t)F * 8, wh + (size_t)col * KT + c * 64 + sor * 8);
            async_copy16(sWL + (size_t)F * 8, wl + (size_t)col * KT + c * 64 + sor * 8);
        }
        __syncthreads();
#pragma unroll
        for (int ks = 0; ks < 2; ks++) {
            const int rowL = wave * 16 + cA;
            const int s8 = ks * 4 + kg;
            bf16x8 ah = ((const bf16x8*)sINb)[rowL * 8 + (s8 ^ (rowL & 7))];
#pragma unroll
            for (int nb = 0; nb < 4; nb++) {
                const int col = nb * 16 + cA;
                const int bs = col * 8 + (s8 ^ (col & 7));
                bf16x8 bh = ((const bf16x8*)sWH)[bs];
                bf16x8 bl = ((const bf16x8*)sWL)[bs];
                acc[nb] = __builtin_amdgcn_mfma_f32_16x16x32_bf16(ah, bh, acc[nb], 0, 0, 0);
                acc[nb] = __builtin_amdgcn_mfma_f32_16x16x32_bf16(ah, bl, acc[nb], 0, 0, 0);
            }
        }
    }
#pragma unroll
    for (int nb = 0; nb < 4; nb++) {
#pragma unroll
        for (int r = 0; r < 4; r++) {
            int n = n0 + wave * 16 + kg * 4 + r;
            if (n < NN)
                h_out[(size_t)n * 64 + nb * 16 + cA] = fmaxf(acc[nb][r], 0.f);
        }
    }
}

// ---- mean pool via binary search on sorted batch (no atomics)
__global__ __launch_bounds__(256)
void k_pool(const float* __restrict__ h, const int* __restrict__ batch,
            float* __restrict__ pool) {
    int g = blockIdx.x;
    auto lb = [&](int v) {
        int lo = 0, hi = NN;
        while (lo < hi) {
            int m = (lo + hi) >> 1;
            if (batch[m] < v) lo = m + 1; else hi = m;
        }
        return lo;
    };
    int st = lb(g), en = lb(g + 1);
    int col = threadIdx.x & 63, chunk = threadIdx.x >> 6;
    float acc = 0.f;
    for (int n = st + chunk; n < en; n += 4) acc += h[(size_t)n * 64 + col];
    __shared__ float s[256];
    s[threadIdx.x] = acc;
    __syncthreads();
    if (chunk == 0) {
        float tot = s[col] + s[64 + col] + s[128 + col] + s[192 + col];
        int c = en - st;
        pool[g * 64 + col] = tot / (float)(c > 1 ? c : 1);
    }
}

// ---- classifier
__global__ __launch_bounds__(256)
void k_final(const float* __restrict__ pool, const float* __restrict__ cw,
             const float* __restrict__ cb, float* __restrict__ out) {
    int t = blockIdx.x * blockDim.x + threadIdx.x;
    if (t >= NG * 10) return;
    int g = t / 10, j = t % 10;
    float acc = 0.f;
#pragma unroll
    for (int k = 0; k < 64; k++) acc += pool[g * 64 + k] * cw[k * 10 + j];
    out[t] = cb[j] + acc;
}

extern "C" void kernel_launch(void* const* d_in, const int* in_sizes, int n_in,
                              void* d_out, int out_size, void* d_ws, size_t ws_size,
                              hipStream_t stream) {
    const int* x      = (const int*)d_in[0];
    const int* ei     = (const int*)d_in[1];
    const int* et     = (const int*)d_in[2];
    const int* batch  = (const int*)d_in[3];
    const float* se   = (const float*)d_in[4];
    const float* ce   = (const float*)d_in[5];
    const float* pw   = (const float*)d_in[6];
    const float* pb   = (const float*)d_in[7];
    const float* w1   = (const float*)d_in[8];
    const float* root1= (const float*)d_in[9];
    const float* b1   = (const float*)d_in[10];
    const float* w2   = (const float*)d_in[11];
    const float* root2= (const float*)d_in[12];
    const float* b2   = (const float*)d_in[13];
    const float* cw   = (const float*)d_in[14];
    const float* cbias= (const float*)d_in[15];
    float* out = (float*)d_out;

    char* ws = (char*)d_ws;
    float*  agg1 = (float*)(ws + AGG_OFF);   // layer-1 fp32 agg
    __bf16* aggb = (__bf16*)(ws + AGG_OFF);  // layer-2 bf16 agg (reuses region)
    int*   hist  = (int*)(ws + HIST_OFF);    // histogram -> end[] after localscan
    int*   start = (int*)(ws + START_OFF);
    int*   csum  = (int*)(ws + CSUM_OFF);
    int*   esrc  = (int*)(ws + ESRC_OFF);
    float* pool  = (float*)(ws + POOL_OFF);
    __bf16* h1b  = (__bf16*)(ws + H1_OFF);
    float* h2    = (float*)(ws + H2_OFF);
    __bf16* wt1h = (__bf16*)(ws + WT1H_OFF);
    __bf16* wt1l = (__bf16*)(ws + WT1L_OFF);
    __bf16* wt2h = (__bf16*)(ws + WT2H_OFF);
    __bf16* wt2l = (__bf16*)(ws + WT2L_OFF);
    float* table = (float*)(ws + TAB_OFF);
    unsigned char* cbarr = (unsigned char*)(ws + CB_OFF);
    unsigned int* rs = (unsigned int*)(ws + RS_OFF);

    // zero the histogram only
    (void)hipMemsetAsync(hist, 0, (size_t)NSEG * 4, stream);

    // fused prep: prepw1 | prepw2 | cbtable | node_cb
    int prep_blocks = 97 + (NN + 255) / 256;
    k_prep_all<<<prep_blocks, 256, 0, stream>>>(x, se, ce, pw, pb, root1, w1, root2, w2,
                                                wt1h, wt1l, wt2h, wt2l, table, cbarr);

    // CSR build (phase A: rank + hist; scan; phase B: atomic-free scatter)
    k_rank<<<(NE + 255) / 256, 256, 0, stream>>>(ei, et, hist, rs);
    k_chunksum<<<NCHUNK, 256, 0, stream>>>(hist, csum);
    k_chunkscan<<<1, 512, 0, stream>>>(csum);
    k_localscan<<<NCHUNK, 256, 0, stream>>>(hist, csum, start);
    k_fill2<<<(NE + 255) / 256, 256, 0, stream>>>(ei, cbarr, start, rs, esrc);

    // layer 1: gather (table, fp32) -> combine (split MFMA) -> h1 bf16
    k_gather_t<<<(NSEG * 8 + 255) / 256, 256, 0, stream>>>(start, hist, esrc, table, agg1);
    k_combine_l1<<<(NN + 63) / 64, 256, 0, stream>>>(table, cbarr, agg1,
                                                     wt1h, wt1l, b1, h1b);
    // layer 2: gather (bf16, 128B/edge) -> combine (bf16 A) -> h2 fp32
    k_gather64<<<(NSEG * 8 + 255) / 256, 256, 0, stream>>>(start, hist, esrc, h1b, aggb);
    k_combine_l2<<<(NN + 63) / 64, 256, 0, stream>>>(h1b, aggb,
                                                     wt2h, wt2l, b2, h2);

    // pooling + classifier
    k_pool<<<NG, 256, 0, stream>>>(h2, batch, pool);
    k_final<<<(NG * 10 + 255) / 256, 256, 0, stream>>>(pool, cw, cbias, out);
}

// Round 15
// 198.213 us; speedup vs baseline: 1.1980x; 1.0051x over previous
//
#include <hip/hip_runtime.h>

#define NN 100000
#define NE 1200000
#define NG 512
#define NSEG (3 * NN)
#define NC 4                      // histogram replication factor
#define CHUNK 1024
#define NCHUNK ((NSEG + CHUNK - 1) / CHUNK)

typedef __bf16 bf16x8 __attribute__((ext_vector_type(8)));
typedef float f32x4 __attribute__((ext_vector_type(4)));

// ---- workspace layout (bytes), all 16B-aligned ----
static constexpr size_t AGG_OFF   = 0;
static constexpr size_t AGG_BYTES = (size_t)NSEG * 32 * 4;              // 38.4MB (l1 fp32 / l2 bf16)
static constexpr size_t HIST_OFF  = AGG_OFF + AGG_BYTES;                // NC*NSEG ints
static constexpr size_t START_OFF = HIST_OFF + (size_t)NC * NSEG * 4;   // NSEG ints
static constexpr size_t END_OFF   = START_OFF + (size_t)NSEG * 4;       // NSEG ints
static constexpr size_t COFF_OFF  = END_OFF + (size_t)NSEG * 4;         // NSEG ints (packed copy prefixes)
static constexpr size_t CSUM_OFF  = COFF_OFF + (size_t)NSEG * 4;        // NCHUNK ints
static constexpr size_t ESRC_OFF  = CSUM_OFF + 4096;                    // NE ints (src|cb<<17)
static constexpr size_t H1_OFF    = ESRC_OFF + (size_t)NE * 4;          // NN*64 bf16
static constexpr size_t H2_OFF    = H1_OFF + (size_t)NN * 64 * 2;       // NN*64 f32
static constexpr size_t WT1H_OFF  = H2_OFF + (size_t)NN * 64 * 4;       // 64*128 bf16
static constexpr size_t WT1L_OFF  = WT1H_OFF + 64 * 128 * 2;
static constexpr size_t WT2H_OFF  = WT1L_OFF + 64 * 128 * 2;            // 64*256 bf16
static constexpr size_t WT2L_OFF  = WT2H_OFF + 64 * 256 * 2;
static constexpr size_t TAB_OFF   = WT2L_OFF + 64 * 256 * 2;            // 256*32 f32
static constexpr size_t CB_OFF    = TAB_OFF + 256 * 32 * 4;             // NN bytes
static constexpr size_t RS_OFF    = ((CB_OFF + NN + 15) / 16) * 16;     // NE uints (rank<<19|seg)

// async global->LDS, 16B per lane
__device__ __forceinline__ void async_copy16(void* lds, const void* g) {
    __builtin_amdgcn_global_load_lds(
        (const __attribute__((address_space(1))) void*)g,
        (__attribute__((address_space(3))) void*)lds, 16, 0, 0);
}

__device__ __forceinline__ void prepw_elem(const float* root, const float* w,
                                           __bf16* wh, __bf16* wl, int cin, int t) {
    int kt = 4 * cin;
    if (t >= 64 * kt) return;
    int j = t / kt, k = t % kt;
    int sidx = k / cin, kk = k % cin;
    float v = (sidx == 0) ? root[kk * 64 + j]
                          : w[((size_t)(sidx - 1) * cin + kk) * 64 + j];
    __bf16 h = (__bf16)v;
    wh[t] = h;
    wl[t] = (__bf16)(v - (float)h);
}

// ---- fused: prep (blocks 0..487) + rank with 4-way replicated hist (blocks 488..)
#define RB_BASE 488
__global__ __launch_bounds__(256)
void k_rank_prep(const int* __restrict__ ei, const int* __restrict__ et,
                 int* __restrict__ hist4, unsigned int* __restrict__ rs,
                 const int* __restrict__ x, const float* __restrict__ se,
                 const float* __restrict__ ce, const float* __restrict__ pw,
                 const float* __restrict__ pb,
                 const float* __restrict__ root1, const float* __restrict__ w1,
                 const float* __restrict__ root2, const float* __restrict__ w2,
                 __bf16* __restrict__ wh1, __bf16* __restrict__ wl1,
                 __bf16* __restrict__ wh2, __bf16* __restrict__ wl2,
                 float* __restrict__ table, unsigned char* __restrict__ cb) {
    int b = blockIdx.x, t = threadIdx.x;
    if (b >= RB_BASE) {
        int e = (b - RB_BASE) * 256 + t;
        if (e >= NE) return;
        int d = ei[NE + e];
        int r = et[e];
        int seg = r * NN + d;
        int c = e & (NC - 1);
        unsigned int rank = (unsigned int)atomicAdd(&hist4[c * NSEG + seg], 1);
        rs[e] = (rank << 19) | (unsigned int)seg;
        return;
    }
    if (b < 32) {
        prepw_elem(root1, w1, wh1, wl1, 32, b * 256 + t);
    } else if (b < 96) {
        prepw_elem(root2, w2, wh2, wl2, 64, (b - 32) * 256 + t);
    } else if (b == 96) {
        __shared__ float sW[16 * 32];
        __shared__ float sB[32];
        for (int i = t; i < 512; i += 256) sW[i] = pw[i];
        if (t < 32) sB[t] = pb[t];
        __syncthreads();
        int cmb = t, s = cmb >> 4, c = cmb & 15;
        float in[16];
#pragma unroll
        for (int k = 0; k < 8; k++) in[k] = se[s * 8 + k];
#pragma unroll
        for (int k = 0; k < 8; k++) in[8 + k] = ce[c * 8 + k];
        float acc[32];
#pragma unroll
        for (int j = 0; j < 32; j++) acc[j] = sB[j];
#pragma unroll
        for (int k = 0; k < 16; k++) {
            float hv = in[k];
#pragma unroll
            for (int j = 0; j < 32; j++) acc[j] += hv * sW[k * 32 + j];
        }
        float* o = table + (size_t)cmb * 32;
#pragma unroll
        for (int j = 0; j < 32; j += 4)
            *(float4*)(o + j) = make_float4(fmaxf(acc[j], 0.f), fmaxf(acc[j + 1], 0.f),
                                            fmaxf(acc[j + 2], 0.f), fmaxf(acc[j + 3], 0.f));
    } else {
        int n = (b - 97) * 256 + t;
        if (n < NN) cb[n] = (unsigned char)(x[2 * n] * 16 + x[2 * n + 1]);
    }
}

// ---- scan pass 1: per-chunk sums over NC hist copies
__global__ __launch_bounds__(256)
void k_chunksum(const int* __restrict__ hist4, int* __restrict__ csum) {
    __shared__ int s[256];
    int b = blockIdx.x, t = threadIdx.x;
    int base = b * CHUNK + t * 4;
    int sum = 0;
#pragma unroll
    for (int k = 0; k < 4; k++) {
        int i = base + k;
        if (i < NSEG) {
#pragma unroll
            for (int c = 0; c < NC; c++) sum += hist4[c * NSEG + i];
        }
    }
    s[t] = sum;
    __syncthreads();
    for (int off = 128; off > 0; off >>= 1) {
        if (t < off) s[t] += s[t + off];
        __syncthreads();
    }
    if (t == 0) csum[b] = s[0];
}

// ---- scan pass 2: exclusive scan of chunk sums
__global__ __launch_bounds__(512)
void k_chunkscan(int* __restrict__ csum) {
    __shared__ int s[512];
    int t = threadIdx.x;
    int v = (t < NCHUNK) ? csum[t] : 0;
    s[t] = v;
    __syncthreads();
    for (int off = 1; off < 512; off <<= 1) {
        int x = (t >= off) ? s[t - off] : 0;
        __syncthreads();
        s[t] += x;
        __syncthreads();
    }
    if (t < NCHUNK) csum[t] = s[t] - v;   // exclusive
}

// ---- scan pass 3: start[], end[], packed copy-prefix coff[]; hist4 left intact
__global__ __launch_bounds__(256)
void k_localscan(const int* __restrict__ hist4, const int* __restrict__ csum,
                 int* __restrict__ start, int* __restrict__ end, int* __restrict__ coff) {
    __shared__ int s[256];
    int b = blockIdx.x, t = threadIdx.x;
    int base = b * CHUNK + t * 4;
    int tot[4], cofv[4];
    int s4 = 0;
#pragma unroll
    for (int k = 0; k < 4; k++) {
        int i = base + k;
        int c0 = 0, c1 = 0, c2 = 0, c3 = 0;
        if (i < NSEG) {
            c0 = hist4[0 * NSEG + i];
            c1 = hist4[1 * NSEG + i];
            c2 = hist4[2 * NSEG + i];
            c3 = hist4[3 * NSEG + i];
        }
        tot[k] = c0 + c1 + c2 + c3;
        cofv[k] = c0 | ((c0 + c1) << 8) | ((c0 + c1 + c2) << 16);
        s4 += tot[k];
    }
    s[t] = s4;
    __syncthreads();
    for (int off = 1; off < 256; off <<= 1) {
        int x = (t >= off) ? s[t - off] : 0;
        __syncthreads();
        s[t] += x;
        __syncthreads();
    }
    int excl = s[t] - s4 + csum[b];
#pragma unroll
    for (int k = 0; k < 4; k++) {
        int i = base + k;
        if (i < NSEG) {
            start[i] = excl;
            end[i] = excl + tot[k];
            coff[i] = cofv[k];
        }
        excl += tot[k];
    }
}

// ---- atomic-free CSR scatter with copy-prefix reconstruction
__global__ __launch_bounds__(256)
void k_fill2(const int* __restrict__ ei, const unsigned char* __restrict__ cb,
             const int* __restrict__ start, const int* __restrict__ coff,
             const unsigned int* __restrict__ rs, int* __restrict__ esrc) {
    int e = blockIdx.x * 256 + threadIdx.x;
    if (e >= NE) return;
    int s = ei[e];
    unsigned int v = rs[e];
    int seg = (int)(v & 0x7FFFFu);
    int rank = (int)(v >> 19);
    int c = e & (NC - 1);
    int off = c ? ((coff[seg] >> (8 * (c - 1))) & 0xFF) : 0;
    int pos = start[seg] + off + rank;
    esrc[pos] = s | ((int)cb[s] << 17);
}

// ---- layer-1 gather from 256-row combo table; fp32 agg
__global__ __launch_bounds__(256)
void k_gather_t(const int* __restrict__ start, const int* __restrict__ end,
                const int* __restrict__ esrc, const float* __restrict__ table,
                float* __restrict__ agg) {
    int tid = blockIdx.x * 256 + threadIdx.x;
    int seg = tid >> 3;
    int p = tid & 7;
    if (seg >= NSEG) return;
    int st = start[seg], en = end[seg];
    float4 acc = make_float4(0.f, 0.f, 0.f, 0.f);
    int i = st;
    for (; i + 4 <= en; i += 4) {
        int v0 = esrc[i], v1 = esrc[i + 1], v2 = esrc[i + 2], v3 = esrc[i + 3];
        float4 a = *(const float4*)(table + ((v0 >> 17) & 0xFF) * 32 + p * 4);
        float4 b = *(const float4*)(table + ((v1 >> 17) & 0xFF) * 32 + p * 4);
        float4 c = *(const float4*)(table + ((v2 >> 17) & 0xFF) * 32 + p * 4);
        float4 d = *(const float4*)(table + ((v3 >> 17) & 0xFF) * 32 + p * 4);
        acc.x += (a.x + b.x) + (c.x + d.x);
        acc.y += (a.y + b.y) + (c.y + d.y);
        acc.z += (a.z + b.z) + (c.z + d.z);
        acc.w += (a.w + b.w) + (c.w + d.w);
    }
    for (; i < en; i++) {
        int v = esrc[i];
        float4 a = *(const float4*)(table + ((v >> 17) & 0xFF) * 32 + p * 4);
        acc.x += a.x; acc.y += a.y; acc.z += a.z; acc.w += a.w;
    }
    int c = en - st;
    float inv = 1.f / (float)(c > 1 ? c : 1);
    acc.x *= inv; acc.y *= inv; acc.z *= inv; acc.w *= inv;
    *(float4*)(agg + (size_t)seg * 32 + p * 4) = acc;
}

// ---- layer-2 gather: bf16 rows (128B/edge); bf16 agg
__global__ __launch_bounds__(256)
void k_gather64(const int* __restrict__ start, const int* __restrict__ end,
                const int* __restrict__ esrc, const __bf16* __restrict__ h,
                __bf16* __restrict__ agg) {
    int tid = blockIdx.x * 256 + threadIdx.x;
    int seg = tid >> 3;
    int p = tid & 7;
    if (seg >= NSEG) return;
    int st = start[seg], en = end[seg];
    float acc[8];
#pragma unroll
    for (int j = 0; j < 8; j++) acc[j] = 0.f;
    int i = st;
    for (; i + 4 <= en; i += 4) {
        int s0 = esrc[i] & 0x1FFFF, s1 = esrc[i + 1] & 0x1FFFF;
        int s2 = esrc[i + 2] & 0x1FFFF, s3 = esrc[i + 3] & 0x1FFFF;
        bf16x8 v0 = *(const bf16x8*)(h + (size_t)s0 * 64 + p * 8);
        bf16x8 v1 = *(const bf16x8*)(h + (size_t)s1 * 64 + p * 8);
        bf16x8 v2 = *(const bf16x8*)(h + (size_t)s2 * 64 + p * 8);
        bf16x8 v3 = *(const bf16x8*)(h + (size_t)s3 * 64 + p * 8);
#pragma unroll
        for (int j = 0; j < 8; j++)
            acc[j] += ((float)v0[j] + (float)v1[j]) + ((float)v2[j] + (float)v3[j]);
    }
    for (; i < en; i++) {
        int s = esrc[i] & 0x1FFFF;
        bf16x8 v = *(const bf16x8*)(h + (size_t)s * 64 + p * 8);
#pragma unroll
        for (int j = 0; j < 8; j++) acc[j] += (float)v[j];
    }
    int c = en - st;
    float inv = 1.f / (float)(c > 1 ? c : 1);
    bf16x8 o;
#pragma unroll
    for (int j = 0; j < 8; j++) o[j] = (__bf16)(acc[j] * inv);
    *(bf16x8*)(agg + (size_t)seg * 64 + p * 8) = o;
}

// split 8 fp32 -> hi/lo bf16x8
__device__ __forceinline__ void split8(float4 a0, float4 a1, bf16x8& hi, bf16x8& lo) {
    float v[8] = {a0.x, a0.y, a0.z, a0.w, a1.x, a1.y, a1.z, a1.w};
#pragma unroll
    for (int i = 0; i < 8; i++) {
        __bf16 h = (__bf16)v[i];
        hi[i] = h;
        lo[i] = (__bf16)(v[i] - (float)h);
    }
}

// ---- layer-1 combine (split-bf16 MFMA, fp32 in, bf16 out)
__global__ __launch_bounds__(256, 1)
void k_combine_l1(const float* __restrict__ table, const unsigned char* __restrict__ cb,
                  const float* __restrict__ agg,
                  const __bf16* __restrict__ wh, const __bf16* __restrict__ wl,
                  const float* __restrict__ bias, __bf16* __restrict__ h_out) {
    constexpr int KT = 128;
    __shared__ float sIN[64 * 64];
    __shared__ __bf16 sWH[64 * 64];
    __shared__ __bf16 sWL[64 * 64];

    const int tid = threadIdx.x;
    const int wave = tid >> 6;
    const int lane = tid & 63;
    const int cA = lane & 15;
    const int kg = lane >> 4;
    const int n0 = blockIdx.x * 64;

    f32x4 acc[4];
#pragma unroll
    for (int nb = 0; nb < 4; nb++) {
        float bv = bias[nb * 16 + cA];
        acc[nb][0] = bv; acc[nb][1] = bv; acc[nb][2] = bv; acc[nb][3] = bv;
    }

    for (int c = 0; c < 2; c++) {
        if (c) __syncthreads();
#pragma unroll
        for (int i = 0; i < 4; i++) {
            int F = tid + i * 256;
            int row = F >> 4, j = F & 15;
            int jor = j ^ (row & 7);
            int n = n0 + row; if (n > NN - 1) n = NN - 1;
            int sidx = 2 * c + (jor >> 3);
            int jj = jor & 7;
            const float* src = (sidx == 0)
                ? table + (size_t)cb[n] * 32 + jj * 4
                : agg + ((size_t)(sidx - 1) * NN + n) * 32 + jj * 4;
            async_copy16(sIN + (size_t)F * 4, src);
        }
#pragma unroll
        for (int i = 0; i < 2; i++) {
            int F = tid + i * 256;
            int col = F >> 3, s = F & 7;
            int sor = s ^ (col & 7);
            async_copy16(sWH + (size_t)F * 8, wh + (size_t)col * KT + c * 64 + sor * 8);
            async_copy16(sWL + (size_t)F * 8, wl + (size_t)col * KT + c * 64 + sor * 8);
        }
        __syncthreads();
#pragma unroll
        for (int ks = 0; ks < 2; ks++) {
            const int rowL = wave * 16 + cA;
            const int jA = ks * 8 + kg * 2;
            float4 a0 = ((const float4*)sIN)[rowL * 16 + (jA ^ (rowL & 7))];
            float4 a1 = ((const float4*)sIN)[rowL * 16 + ((jA + 1) ^ (rowL & 7))];
            bf16x8 ah, al;
            split8(a0, a1, ah, al);
            const int k8 = ks * 4 + kg;
#pragma unroll
            for (int nb = 0; nb < 4; nb++) {
                const int col = nb * 16 + cA;
                const int bs = col * 8 + (k8 ^ (col & 7));
                bf16x8 bh = ((const bf16x8*)sWH)[bs];
                bf16x8 bl = ((const bf16x8*)sWL)[bs];
                acc[nb] = __builtin_amdgcn_mfma_f32_16x16x32_bf16(ah, bh, acc[nb], 0, 0, 0);
                acc[nb] = __builtin_amdgcn_mfma_f32_16x16x32_bf16(al, bh, acc[nb], 0, 0, 0);
                acc[nb] = __builtin_amdgcn_mfma_f32_16x16x32_bf16(ah, bl, acc[nb], 0, 0, 0);
                acc[nb] = __builtin_amdgcn_mfma_f32_16x16x32_bf16(al, bl, acc[nb], 0, 0, 0);
            }
        }
    }
#pragma unroll
    for (int nb = 0; nb < 4; nb++) {
#pragma unroll
        for (int r = 0; r < 4; r++) {
            int n = n0 + wave * 16 + kg * 4 + r;
            if (n < NN)
                h_out[(size_t)n * 64 + nb * 16 + cA] = (__bf16)fmaxf(acc[nb][r], 0.f);
        }
    }
}

// ---- layer-2 combine (bf16 A, split-bf16 weights; fp32 out)
__global__ __launch_bounds__(256, 1)
void k_combine_l2(const __bf16* __restrict__ h1b, const __bf16* __restrict__ aggb,
                  const __bf16* __restrict__ wh, const __bf16* __restrict__ wl,
                  const float* __restrict__ bias, float* __restrict__ h_out) {
    constexpr int KT = 256;
    __shared__ __bf16 sINb[64 * 64];
    __shared__ __bf16 sWH[64 * 64];
    __shared__ __bf16 sWL[64 * 64];

    const int tid = threadIdx.x;
    const int wave = tid >> 6;
    const int lane = tid & 63;
    const int cA = lane & 15;
    const int kg = lane >> 4;
    const int n0 = blockIdx.x * 64;

    f32x4 acc[4];
#pragma unroll
    for (int nb = 0; nb < 4; nb++) {
        float bv = bias[nb * 16 + cA];
        acc[nb][0] = bv; acc[nb][1] = bv; acc[nb][2] = bv; acc[nb][3] = bv;
    }

    for (int c = 0; c < 4; c++) {
        if (c) __syncthreads();
#pragma unroll
        for (int i = 0; i < 2; i++) {
            int F = tid + i * 256;
            int row = F >> 3, j = F & 7;
            int jor = j ^ (row & 7);
            int n = n0 + row; if (n > NN - 1) n = NN - 1;
            const __bf16* src = (c == 0)
                ? h1b + (size_t)n * 64 + jor * 8
                : aggb + ((size_t)(c - 1) * NN + n) * 64 + jor * 8;
            async_copy16(sINb + (size_t)F * 8, src);
        }
#pragma unroll
        for (int i = 0; i < 2; i++) {
            int F = tid + i * 256;
            int col = F >> 3, s = F & 7;
            int sor = s ^ (col & 7);
            async_copy16(sWH + (size_t)F * 8, wh + (size_t)col * KT + c * 64 + sor * 8);
            async_copy16(sWL + (size_t)F * 8, wl + (size_t)col * KT + c * 64 + sor * 8);
        }
        __syncthreads();
#pragma unroll
        for (int ks = 0; ks < 2; ks++) {
            const int rowL = wave * 16 + cA;
            const int s8 = ks * 4 + kg;
            bf16x8 ah = ((const bf16x8*)sINb)[rowL * 8 + (s8 ^ (rowL & 7))];
#pragma unroll
            for (int nb = 0; nb < 4; nb++) {
                const int col = nb * 16 + cA;
                const int bs = col * 8 + (s8 ^ (col & 7));
                bf16x8 bh = ((const bf16x8*)sWH)[bs];
                bf16x8 bl = ((const bf16x8*)sWL)[bs];
                acc[nb] = __builtin_amdgcn_mfma_f32_16x16x32_bf16(ah, bh, acc[nb], 0, 0, 0);
                acc[nb] = __builtin_amdgcn_mfma_f32_16x16x32_bf16(ah, bl, acc[nb], 0, 0, 0);
            }
        }
    }
#pragma unroll
    for (int nb = 0; nb < 4; nb++) {
#pragma unroll
        for (int r = 0; r < 4; r++) {
            int n = n0 + wave * 16 + kg * 4 + r;
            if (n < NN)
                h_out[(size_t)n * 64 + nb * 16 + cA] = fmaxf(acc[nb][r], 0.f);
        }
    }
}

// ---- fused mean-pool + classifier: block g -> out[g][0..9]
__global__ __launch_bounds__(256)
void k_pool_final(const float* __restrict__ h, const int* __restrict__ batch,
                  const float* __restrict__ cw, const float* __restrict__ cbias,
                  float* __restrict__ out) {
    int g = blockIdx.x;
    auto lb = [&](int v) {
        int lo = 0, hi = NN;
        while (lo < hi) {
            int m = (lo + hi) >> 1;
            if (batch[m] < v) lo = m + 1; else hi = m;
        }
        return lo;
    };
    int st = lb(g), en = lb(g + 1);
    int col = threadIdx.x & 63, chunk = threadIdx.x >> 6;
    float acc = 0.f;
    for (int n = st + chunk; n < en; n += 4) acc += h[(size_t)n * 64 + col];
    __shared__ float s[256];
    __shared__ float mean[64];
    s[threadIdx.x] = acc;
    __syncthreads();
    if (chunk == 0) {
        float tot = s[col] + s[64 + col] + s[128 + col] + s[192 + col];
        int c = en - st;
        mean[col] = tot / (float)(c > 1 ? c : 1);
    }
    __syncthreads();
    if (threadIdx.x < 10) {
        int j = threadIdx.x;
        float o = cbias[j];
#pragma unroll
        for (int k = 0; k < 64; k++) o += mean[k] * cw[k * 10 + j];
        out[g * 10 + j] = o;
    }
}

extern "C" void kernel_launch(void* const* d_in, const int* in_sizes, int n_in,
                              void* d_out, int out_size, void* d_ws, size_t ws_size,
                              hipStream_t stream) {
    const int* x      = (const int*)d_in[0];
    const int* ei     = (const int*)d_in[1];
    const int* et     = (const int*)d_in[2];
    const int* batch  = (const int*)d_in[3];
    const float* se   = (const float*)d_in[4];
    const float* ce   = (const float*)d_in[5];
    const float* pw   = (const float*)d_in[6];
    const float* pb   = (const float*)d_in[7];
    const float* w1   = (const float*)d_in[8];
    const float* root1= (const float*)d_in[9];
    const float* b1   = (const float*)d_in[10];
    const float* w2   = (const float*)d_in[11];
    const float* root2= (const float*)d_in[12];
    const float* b2   = (const float*)d_in[13];
    const float* cw   = (const float*)d_in[14];
    const float* cbias= (const float*)d_in[15];
    float* out = (float*)d_out;

    char* ws = (char*)d_ws;
    float*  agg1 = (float*)(ws + AGG_OFF);
    __bf16* aggb = (__bf16*)(ws + AGG_OFF);
    int*   hist4 = (int*)(ws + HIST_OFF);
    int*   start = (int*)(ws + START_OFF);
    int*   end   = (int*)(ws + END_OFF);
    int*   coff  = (int*)(ws + COFF_OFF);
    int*   csum  = (int*)(ws + CSUM_OFF);
    int*   esrc  = (int*)(ws + ESRC_OFF);
    __bf16* h1b  = (__bf16*)(ws + H1_OFF);
    float* h2    = (float*)(ws + H2_OFF);
    __bf16* wt1h = (__bf16*)(ws + WT1H_OFF);
    __bf16* wt1l = (__bf16*)(ws + WT1L_OFF);
    __bf16* wt2h = (__bf16*)(ws + WT2H_OFF);
    __bf16* wt2l = (__bf16*)(ws + WT2L_OFF);
    float* table = (float*)(ws + TAB_OFF);
    unsigned char* cbarr = (unsigned char*)(ws + CB_OFF);
    unsigned int* rs = (unsigned int*)(ws + RS_OFF);

    // zero the replicated histogram
    (void)hipMemsetAsync(hist4, 0, (size_t)NC * NSEG * 4, stream);

    // fused prep + rank
    int rank_blocks = RB_BASE + (NE + 255) / 256;
    k_rank_prep<<<rank_blocks, 256, 0, stream>>>(ei, et, hist4, rs,
                                                 x, se, ce, pw, pb, root1, w1, root2, w2,
                                                 wt1h, wt1l, wt2h, wt2l, table, cbarr);

    // scan
    k_chunksum<<<NCHUNK, 256, 0, stream>>>(hist4, csum);
    k_chunkscan<<<1, 512, 0, stream>>>(csum);
    k_localscan<<<NCHUNK, 256, 0, stream>>>(hist4, csum, start, end, coff);
    k_fill2<<<(NE + 255) / 256, 256, 0, stream>>>(ei, cbarr, start, coff, rs, esrc);

    // layer 1
    k_gather_t<<<(NSEG * 8 + 255) / 256, 256, 0, stream>>>(start, end, esrc, table, agg1);
    k_combine_l1<<<(NN + 63) / 64, 256, 0, stream>>>(table, cbarr, agg1,
                                                     wt1h, wt1l, b1, h1b);
    // layer 2
    k_gather64<<<(NSEG * 8 + 255) / 256, 256, 0, stream>>>(start, end, esrc, h1b, aggb);
    k_combine_l2<<<(NN + 63) / 64, 256, 0, stream>>>(h1b, aggb,
                                                     wt2h, wt2l, b2, h2);

    // fused pooling + classifier
    k_pool_final<<<NG, 256, 0, stream>>>(h2, batch, cw, cbias, out);
}